// Round 1
// baseline (756.353 us; speedup 1.0000x reference)
//
#include <hip/hip_runtime.h>

// ---------------- CSR construction ----------------

__global__ void deg_kernel(const int* __restrict__ dst, int* __restrict__ deg, int E) {
    int e = blockIdx.x * 256 + threadIdx.x;
    if (e < E) atomicAdd(&deg[dst[e]], 1);
}

__global__ void dinv_kernel(const int* __restrict__ deg, float* __restrict__ dinv, int n) {
    int i = blockIdx.x * 256 + threadIdx.x;
    if (i < n) dinv[i] = rsqrtf((float)(deg[i] + 1));   // +1 self-loop; deg+1 >= 1
}

__global__ void scan_blocksum(const int* __restrict__ deg, int* __restrict__ bsum, int n) {
    int i = blockIdx.x * 256 + threadIdx.x;
    int v = (i < n) ? (deg[i] + 1) : 0;
    for (int off = 32; off > 0; off >>= 1) v += __shfl_down(v, off, 64);
    __shared__ int ws[4];
    if ((threadIdx.x & 63) == 0) ws[threadIdx.x >> 6] = v;
    __syncthreads();
    if (threadIdx.x == 0) bsum[blockIdx.x] = ws[0] + ws[1] + ws[2] + ws[3];
}

__global__ void scan_offsets(const int* __restrict__ bsum, int* __restrict__ boff, int nblk) {
    __shared__ int buf[256];
    int tid = threadIdx.x;
    int v = (tid < nblk) ? bsum[tid] : 0;
    buf[tid] = v;
    __syncthreads();
    for (int off = 1; off < 256; off <<= 1) {
        int t = (tid >= off) ? buf[tid - off] : 0;
        __syncthreads();
        buf[tid] += t;
        __syncthreads();
    }
    if (tid < nblk) boff[tid] = buf[tid] - v;   // exclusive
}

__global__ void scan_rowptr(const int* __restrict__ deg, const int* __restrict__ boff,
                            int* __restrict__ row_ptr, int* __restrict__ cursor, int n) {
    __shared__ int buf[256];
    int tid = threadIdx.x;
    int i = blockIdx.x * 256 + tid;
    int v = (i < n) ? (deg[i] + 1) : 0;
    buf[tid] = v;
    __syncthreads();
    for (int off = 1; off < 256; off <<= 1) {
        int t = (tid >= off) ? buf[tid - off] : 0;
        __syncthreads();
        buf[tid] += t;
        __syncthreads();
    }
    int excl = buf[tid] - v + boff[blockIdx.x];
    if (i < n) { row_ptr[i] = excl; cursor[i] = excl; }
    if (i == n - 1) row_ptr[n] = excl + v;
}

__global__ void fill_kernel(const int* __restrict__ src, const int* __restrict__ dst,
                            int* __restrict__ cursor, int* __restrict__ csr_src, int E, int n) {
    int e = blockIdx.x * 256 + threadIdx.x;
    if (e >= E + n) return;
    int s, d;
    if (e < E) { s = src[e]; d = dst[e]; } else { s = e - E; d = s; }
    int pos = atomicAdd(&cursor[d], 1);
    csr_src[pos] = s;
}

// ---------------- Aggregation: out[n] = dinv[n] * sum_s dinv[s] * in[s] ----------------
// One wave per node; lane = feature column (C=64: 1 float, C=128: float2).

template<int C>
__global__ __launch_bounds__(256) void agg_kernel(
        const float* __restrict__ in, float* __restrict__ out,
        const int* __restrict__ row_ptr, const int* __restrict__ csr_src,
        const float* __restrict__ dinv, int n) {
    int node = blockIdx.x * 4 + (threadIdx.x >> 6);
    int lane = threadIdx.x & 63;
    if (node >= n) return;
    int beg = row_ptr[node], end = row_ptr[node + 1];
    if (C == 64) {
        float acc = 0.f;
        for (int i = beg; i < end; ++i) {
            int s = csr_src[i];
            acc = fmaf(dinv[s], in[(size_t)s * 64 + lane], acc);
        }
        out[(size_t)node * 64 + lane] = acc * dinv[node];
    } else {
        const float2* in2 = (const float2*)in;
        float2 acc = make_float2(0.f, 0.f);
        for (int i = beg; i < end; ++i) {
            int s = csr_src[i];
            float w = dinv[s];
            float2 v = in2[(size_t)s * 64 + lane];
            acc.x = fmaf(w, v.x, acc.x);
            acc.y = fmaf(w, v.y, acc.y);
        }
        float dn = dinv[node];
        ((float2*)out)[(size_t)node * 64 + lane] = make_float2(acc.x * dn, acc.y * dn);
    }
}

// ---------------- GEMM + bias (+ReLU): [n,K] @ [K,128] ----------------
// Block: 32 rows x 128 cols, 256 threads, 4x4 register micro-tile, W + A staged in LDS.

template<int K, bool RELU>
__global__ __launch_bounds__(256) void gemm_bias(
        const float* __restrict__ A, const float* __restrict__ W,
        const float* __restrict__ b, float* __restrict__ out, int n) {
    __shared__ float Ws[K * 128];
    __shared__ float As[32 * K];
    int tid = threadIdx.x;
    for (int i = tid * 4; i < K * 128; i += 256 * 4)
        *(float4*)&Ws[i] = *(const float4*)&W[i];
    int row0 = blockIdx.x * 32;
    for (int i = tid * 4; i < 32 * K; i += 256 * 4) {
        int r = i / K;
        int k = i - r * K;
        int gr = row0 + r;
        float4 v = make_float4(0.f, 0.f, 0.f, 0.f);
        if (gr < n) v = *(const float4*)&A[(size_t)gr * K + k];
        *(float4*)&As[i] = v;
    }
    __syncthreads();
    int tx = tid & 31;   // cols tx*4 .. tx*4+3
    int ty = tid >> 5;   // rows ty*4 .. ty*4+3
    float acc[4][4];
    float4 bv = *(const float4*)&b[tx * 4];
#pragma unroll
    for (int i = 0; i < 4; ++i) { acc[i][0] = bv.x; acc[i][1] = bv.y; acc[i][2] = bv.z; acc[i][3] = bv.w; }
    for (int k = 0; k < K; ++k) {
        float4 wv = *(const float4*)&Ws[k * 128 + tx * 4];
        float av[4];
#pragma unroll
        for (int i = 0; i < 4; ++i) av[i] = As[(ty * 4 + i) * K + k];
#pragma unroll
        for (int i = 0; i < 4; ++i) {
            acc[i][0] = fmaf(av[i], wv.x, acc[i][0]);
            acc[i][1] = fmaf(av[i], wv.y, acc[i][1]);
            acc[i][2] = fmaf(av[i], wv.z, acc[i][2]);
            acc[i][3] = fmaf(av[i], wv.w, acc[i][3]);
        }
    }
#pragma unroll
    for (int i = 0; i < 4; ++i) {
        int gr = row0 + ty * 4 + i;
        if (gr < n) {
            float4 o;
            o.x = RELU ? fmaxf(acc[i][0], 0.f) : acc[i][0];
            o.y = RELU ? fmaxf(acc[i][1], 0.f) : acc[i][1];
            o.z = RELU ? fmaxf(acc[i][2], 0.f) : acc[i][2];
            o.w = RELU ? fmaxf(acc[i][3], 0.f) : acc[i][3];
            *(float4*)&out[(size_t)gr * 128 + tx * 4] = o;
        }
    }
}

// ---------------- Pooling + head ----------------

__global__ void count_kernel(const int* __restrict__ batch, int* __restrict__ gcnt, int n) {
    int i = blockIdx.x * 256 + threadIdx.x;
    if (i < n) atomicAdd(&gcnt[batch[i]], 1);
}

__global__ void gstart_kernel(const int* __restrict__ gcnt, int* __restrict__ gstart, int G) {
    if (threadIdx.x == 0 && blockIdx.x == 0) {
        int s = 0;
        for (int g = 0; g < G; ++g) { gstart[g] = s; s += gcnt[g]; }
        gstart[G] = s;
    }
}

__global__ void pool_kernel(const float* __restrict__ h, const int* __restrict__ gstart,
                            float* __restrict__ gout) {
    __shared__ float part[512];
    int g = blockIdx.x;
    int tid = threadIdx.x;
    int c = tid & 127, rs = tid >> 7;
    int beg = gstart[g], end = gstart[g + 1];
    float acc = 0.f;
    for (int nrow = beg + rs; nrow < end; nrow += 4)
        acc += h[(size_t)nrow * 128 + c];
    part[tid] = acc;
    __syncthreads();
    if (rs == 0) {
        float t = part[c] + part[c + 128] + part[c + 256] + part[c + 384];
        gout[g * 128 + c] = t / fmaxf((float)(end - beg), 1.f);
    }
}

__global__ void head_kernel(const float* __restrict__ g, const float* __restrict__ Wh,
                            const float* __restrict__ bh, float* __restrict__ out, int G) {
    int tid = blockIdx.x * blockDim.x + threadIdx.x;
    if (tid >= G * 8) return;
    int gi = tid >> 3, o = tid & 7;
    float acc = bh[o];
    for (int k = 0; k < 128; ++k)
        acc = fmaf(g[gi * 128 + k], Wh[k * 8 + o], acc);
    out[tid] = acc;
}

// ---------------- Launch ----------------

extern "C" void kernel_launch(void* const* d_in, const int* in_sizes, int n_in,
                              void* d_out, int out_size, void* d_ws, size_t ws_size,
                              hipStream_t stream) {
    const float* x  = (const float*)d_in[0];
    const float* W1 = (const float*)d_in[1];
    const float* b1 = (const float*)d_in[2];
    const float* W2 = (const float*)d_in[3];
    const float* b2 = (const float*)d_in[4];
    const float* W3 = (const float*)d_in[5];
    const float* b3 = (const float*)d_in[6];
    const float* Wh = (const float*)d_in[7];
    const float* bh = (const float*)d_in[8];
    const int* edge_index = (const int*)d_in[9];
    const int* batch = (const int*)d_in[10];
    (void)n_in; (void)ws_size;

    const int N = in_sizes[10];
    const int E = in_sizes[9] / 2;
    const int G = out_size / 8;
    const int* esrc = edge_index;
    const int* edst = edge_index + E;

    size_t off = 0;
    auto take = [&](size_t bytes) {
        void* p = (char*)d_ws + off;
        off += (bytes + 255) & ~(size_t)255;
        return p;
    };
    int*   deg     = (int*)take((size_t)N * 4);
    float* dinv    = (float*)take((size_t)N * 4);
    int*   row_ptr = (int*)take((size_t)(N + 1) * 4);
    int*   cursor  = (int*)take((size_t)N * 4);
    int*   csr_src = (int*)take((size_t)(E + N) * 4);
    int*   bsum    = (int*)take(256 * 4);
    int*   boff    = (int*)take(256 * 4);
    int*   gcnt    = (int*)take((size_t)G * 4);
    int*   gstart  = (int*)take((size_t)(G + 1) * 4);
    float* gpool   = (float*)take((size_t)G * 128 * 4);
    float* bufA    = (float*)take((size_t)N * 128 * 4);
    float* bufB    = (float*)take((size_t)N * 128 * 4);

    int nblk = (N + 255) / 256;   // 196 for N=50000 (fits single-block scan_offsets)

    hipMemsetAsync(deg, 0, (size_t)N * 4, stream);
    hipMemsetAsync(gcnt, 0, (size_t)G * 4, stream);

    deg_kernel<<<(E + 255) / 256, 256, 0, stream>>>(edst, deg, E);
    dinv_kernel<<<nblk, 256, 0, stream>>>(deg, dinv, N);
    scan_blocksum<<<nblk, 256, 0, stream>>>(deg, bsum, N);
    scan_offsets<<<1, 256, 0, stream>>>(bsum, boff, nblk);
    scan_rowptr<<<nblk, 256, 0, stream>>>(deg, boff, row_ptr, cursor, N);
    fill_kernel<<<(E + N + 255) / 256, 256, 0, stream>>>(esrc, edst, cursor, csr_src, E, N);

    // Layer 1: aggregate 64-wide input first (Agg(x)@W1 == Agg(x@W1)), then GEMM+bias+ReLU
    agg_kernel<64><<<(N + 3) / 4, 256, 0, stream>>>(x, bufB, row_ptr, csr_src, dinv, N);
    gemm_bias<64, true><<<(N + 31) / 32, 256, 0, stream>>>(bufB, W1, b1, bufA, N);
    // Layer 2
    agg_kernel<128><<<(N + 3) / 4, 256, 0, stream>>>(bufA, bufB, row_ptr, csr_src, dinv, N);
    gemm_bias<128, true><<<(N + 31) / 32, 256, 0, stream>>>(bufB, W2, b2, bufA, N);
    // Layer 3 (no ReLU)
    agg_kernel<128><<<(N + 3) / 4, 256, 0, stream>>>(bufA, bufB, row_ptr, csr_src, dinv, N);
    gemm_bias<128, false><<<(N + 31) / 32, 256, 0, stream>>>(bufB, W3, b3, bufA, N);

    // Pool (batch is sorted -> contiguous per-graph row ranges) + head
    count_kernel<<<nblk, 256, 0, stream>>>(batch, gcnt, N);
    gstart_kernel<<<1, 64, 0, stream>>>(gcnt, gstart, G);
    pool_kernel<<<G, 512, 0, stream>>>(bufA, gstart, gpool);
    head_kernel<<<(G * 8 + 255) / 256, 256, 0, stream>>>(gpool, Wh, bh, (float*)d_out, G);
}

// Round 2
// 518.992 us; speedup vs baseline: 1.4574x; 1.4574x over previous
//
#include <hip/hip_runtime.h>

// ---------------- CSR construction ----------------

__global__ void deg_kernel(const int* __restrict__ dst, int* __restrict__ deg, int E) {
    int e = blockIdx.x * 256 + threadIdx.x;
    if (e < E) atomicAdd(&deg[dst[e]], 1);
}

__global__ void dinv_kernel(const int* __restrict__ deg, float* __restrict__ dinv, int n) {
    int i = blockIdx.x * 256 + threadIdx.x;
    if (i < n) dinv[i] = rsqrtf((float)(deg[i] + 1));   // +1 self-loop; deg+1 >= 1
}

__global__ void scan_blocksum(const int* __restrict__ deg, int* __restrict__ bsum, int n) {
    int i = blockIdx.x * 256 + threadIdx.x;
    int v = (i < n) ? (deg[i] + 1) : 0;
    for (int off = 32; off > 0; off >>= 1) v += __shfl_down(v, off, 64);
    __shared__ int ws[4];
    if ((threadIdx.x & 63) == 0) ws[threadIdx.x >> 6] = v;
    __syncthreads();
    if (threadIdx.x == 0) bsum[blockIdx.x] = ws[0] + ws[1] + ws[2] + ws[3];
}

__global__ void scan_offsets(const int* __restrict__ bsum, int* __restrict__ boff, int nblk) {
    __shared__ int buf[256];
    int tid = threadIdx.x;
    int v = (tid < nblk) ? bsum[tid] : 0;
    buf[tid] = v;
    __syncthreads();
    for (int off = 1; off < 256; off <<= 1) {
        int t = (tid >= off) ? buf[tid - off] : 0;
        __syncthreads();
        buf[tid] += t;
        __syncthreads();
    }
    if (tid < nblk) boff[tid] = buf[tid] - v;   // exclusive
}

__global__ void scan_rowptr(const int* __restrict__ deg, const int* __restrict__ boff,
                            int* __restrict__ row_ptr, int* __restrict__ cursor, int n) {
    __shared__ int buf[256];
    int tid = threadIdx.x;
    int i = blockIdx.x * 256 + tid;
    int v = (i < n) ? (deg[i] + 1) : 0;
    buf[tid] = v;
    __syncthreads();
    for (int off = 1; off < 256; off <<= 1) {
        int t = (tid >= off) ? buf[tid - off] : 0;
        __syncthreads();
        buf[tid] += t;
        __syncthreads();
    }
    int excl = buf[tid] - v + boff[blockIdx.x];
    if (i < n) { row_ptr[i] = excl; cursor[i] = excl; }
    if (i == n - 1) row_ptr[n] = excl + v;
}

__global__ void fill_kernel(const int* __restrict__ src, const int* __restrict__ dst,
                            int* __restrict__ cursor, int* __restrict__ csr_src, int E, int n) {
    int e = blockIdx.x * 256 + threadIdx.x;
    if (e >= E + n) return;
    int s, d;
    if (e < E) { s = src[e]; d = dst[e]; } else { s = e - E; d = s; }
    int pos = atomicAdd(&cursor[d], 1);
    csr_src[pos] = s;
}

// ---------------- Aggregation: out[n] = dinv[n] * sum_s dinv[s] * in[s] ----------------
// One wave per node; lane = feature column (C=64: 1 float, C=128: float2).

template<int C>
__global__ __launch_bounds__(256) void agg_kernel(
        const float* __restrict__ in, float* __restrict__ out,
        const int* __restrict__ row_ptr, const int* __restrict__ csr_src,
        const float* __restrict__ dinv, int n) {
    int node = blockIdx.x * 4 + (threadIdx.x >> 6);
    int lane = threadIdx.x & 63;
    if (node >= n) return;
    int beg = row_ptr[node], end = row_ptr[node + 1];
    if (C == 64) {
        float acc = 0.f;
        for (int i = beg; i < end; ++i) {
            int s = csr_src[i];
            acc = fmaf(dinv[s], in[(size_t)s * 64 + lane], acc);
        }
        out[(size_t)node * 64 + lane] = acc * dinv[node];
    } else {
        const float2* in2 = (const float2*)in;
        float2 acc = make_float2(0.f, 0.f);
        for (int i = beg; i < end; ++i) {
            int s = csr_src[i];
            float w = dinv[s];
            float2 v = in2[(size_t)s * 64 + lane];
            acc.x = fmaf(w, v.x, acc.x);
            acc.y = fmaf(w, v.y, acc.y);
        }
        float dn = dinv[node];
        ((float2*)out)[(size_t)node * 64 + lane] = make_float2(acc.x * dn, acc.y * dn);
    }
}

// ---------------- GEMM + bias (+ReLU): [n,K] @ [K,128] ----------------
// Block: 32 rows x 128 cols, 256 threads, 4x4 register micro-tile, W + A staged in LDS.

template<int K, bool RELU>
__global__ __launch_bounds__(256) void gemm_bias(
        const float* __restrict__ A, const float* __restrict__ W,
        const float* __restrict__ b, float* __restrict__ out, int n) {
    __shared__ float Ws[K * 128];
    __shared__ float As[32 * K];
    int tid = threadIdx.x;
    for (int i = tid * 4; i < K * 128; i += 256 * 4)
        *(float4*)&Ws[i] = *(const float4*)&W[i];
    int row0 = blockIdx.x * 32;
    for (int i = tid * 4; i < 32 * K; i += 256 * 4) {
        int r = i / K;
        int k = i - r * K;
        int gr = row0 + r;
        float4 v = make_float4(0.f, 0.f, 0.f, 0.f);
        if (gr < n) v = *(const float4*)&A[(size_t)gr * K + k];
        *(float4*)&As[i] = v;
    }
    __syncthreads();
    int tx = tid & 31;   // cols tx*4 .. tx*4+3
    int ty = tid >> 5;   // rows ty*4 .. ty*4+3
    float acc[4][4];
    float4 bv = *(const float4*)&b[tx * 4];
#pragma unroll
    for (int i = 0; i < 4; ++i) { acc[i][0] = bv.x; acc[i][1] = bv.y; acc[i][2] = bv.z; acc[i][3] = bv.w; }
    for (int k = 0; k < K; ++k) {
        float4 wv = *(const float4*)&Ws[k * 128 + tx * 4];
        float av[4];
#pragma unroll
        for (int i = 0; i < 4; ++i) av[i] = As[(ty * 4 + i) * K + k];
#pragma unroll
        for (int i = 0; i < 4; ++i) {
            acc[i][0] = fmaf(av[i], wv.x, acc[i][0]);
            acc[i][1] = fmaf(av[i], wv.y, acc[i][1]);
            acc[i][2] = fmaf(av[i], wv.z, acc[i][2]);
            acc[i][3] = fmaf(av[i], wv.w, acc[i][3]);
        }
    }
#pragma unroll
    for (int i = 0; i < 4; ++i) {
        int gr = row0 + ty * 4 + i;
        if (gr < n) {
            float4 o;
            o.x = RELU ? fmaxf(acc[i][0], 0.f) : acc[i][0];
            o.y = RELU ? fmaxf(acc[i][1], 0.f) : acc[i][1];
            o.z = RELU ? fmaxf(acc[i][2], 0.f) : acc[i][2];
            o.w = RELU ? fmaxf(acc[i][3], 0.f) : acc[i][3];
            *(float4*)&out[(size_t)gr * 128 + tx * 4] = o;
        }
    }
}

// ---------------- Pooling + head ----------------

// batch is sorted: gstart[g] = lower_bound(batch, g). No atomics, handles empty graphs.
__global__ void gstart_bs(const int* __restrict__ batch, int* __restrict__ gstart,
                          int n, int G) {
    int g = blockIdx.x * blockDim.x + threadIdx.x;
    if (g > G) return;
    int lo = 0, hi = n;
    while (lo < hi) {
        int mid = (lo + hi) >> 1;
        if (batch[mid] < g) lo = mid + 1; else hi = mid;
    }
    gstart[g] = lo;
}

__global__ void pool_kernel(const float* __restrict__ h, const int* __restrict__ gstart,
                            float* __restrict__ gout) {
    __shared__ float part[512];
    int g = blockIdx.x;
    int tid = threadIdx.x;
    int c = tid & 127, rs = tid >> 7;
    int beg = gstart[g], end = gstart[g + 1];
    float acc = 0.f;
    for (int nrow = beg + rs; nrow < end; nrow += 4)
        acc += h[(size_t)nrow * 128 + c];
    part[tid] = acc;
    __syncthreads();
    if (rs == 0) {
        float t = part[c] + part[c + 128] + part[c + 256] + part[c + 384];
        gout[g * 128 + c] = t / fmaxf((float)(end - beg), 1.f);
    }
}

__global__ void head_kernel(const float* __restrict__ g, const float* __restrict__ Wh,
                            const float* __restrict__ bh, float* __restrict__ out, int G) {
    int tid = blockIdx.x * blockDim.x + threadIdx.x;
    if (tid >= G * 8) return;
    int gi = tid >> 3, o = tid & 7;
    float acc = bh[o];
    for (int k = 0; k < 128; ++k)
        acc = fmaf(g[gi * 128 + k], Wh[k * 8 + o], acc);
    out[tid] = acc;
}

// ---------------- Launch ----------------

extern "C" void kernel_launch(void* const* d_in, const int* in_sizes, int n_in,
                              void* d_out, int out_size, void* d_ws, size_t ws_size,
                              hipStream_t stream) {
    const float* x  = (const float*)d_in[0];
    const float* W1 = (const float*)d_in[1];
    const float* b1 = (const float*)d_in[2];
    const float* W2 = (const float*)d_in[3];
    const float* b2 = (const float*)d_in[4];
    const float* W3 = (const float*)d_in[5];
    const float* b3 = (const float*)d_in[6];
    const float* Wh = (const float*)d_in[7];
    const float* bh = (const float*)d_in[8];
    const int* edge_index = (const int*)d_in[9];
    const int* batch = (const int*)d_in[10];
    (void)n_in; (void)ws_size;

    const int N = in_sizes[10];
    const int E = in_sizes[9] / 2;
    const int G = out_size / 8;
    const int* esrc = edge_index;
    const int* edst = edge_index + E;

    size_t off = 0;
    auto take = [&](size_t bytes) {
        void* p = (char*)d_ws + off;
        off += (bytes + 255) & ~(size_t)255;
        return p;
    };
    int*   deg     = (int*)take((size_t)N * 4);
    float* dinv    = (float*)take((size_t)N * 4);
    int*   row_ptr = (int*)take((size_t)(N + 1) * 4);
    int*   cursor  = (int*)take((size_t)N * 4);
    int*   csr_src = (int*)take((size_t)(E + N) * 4);
    int*   bsum    = (int*)take(256 * 4);
    int*   boff    = (int*)take(256 * 4);
    int*   gstart  = (int*)take((size_t)(G + 1) * 4);
    float* gpool   = (float*)take((size_t)G * 128 * 4);
    float* bufA    = (float*)take((size_t)N * 128 * 4);
    float* bufB    = (float*)take((size_t)N * 128 * 4);

    int nblk = (N + 255) / 256;   // 196 for N=50000 (fits single-block scan_offsets)

    hipMemsetAsync(deg, 0, (size_t)N * 4, stream);

    deg_kernel<<<(E + 255) / 256, 256, 0, stream>>>(edst, deg, E);
    dinv_kernel<<<nblk, 256, 0, stream>>>(deg, dinv, N);
    scan_blocksum<<<nblk, 256, 0, stream>>>(deg, bsum, N);
    scan_offsets<<<1, 256, 0, stream>>>(bsum, boff, nblk);
    scan_rowptr<<<nblk, 256, 0, stream>>>(deg, boff, row_ptr, cursor, N);
    fill_kernel<<<(E + N + 255) / 256, 256, 0, stream>>>(esrc, edst, cursor, csr_src, E, N);

    // Layer 1: aggregate 64-wide input first (Agg(x)@W1 == Agg(x@W1)), then GEMM+bias+ReLU
    agg_kernel<64><<<(N + 3) / 4, 256, 0, stream>>>(x, bufB, row_ptr, csr_src, dinv, N);
    gemm_bias<64, true><<<(N + 31) / 32, 256, 0, stream>>>(bufB, W1, b1, bufA, N);
    // Layer 2
    agg_kernel<128><<<(N + 3) / 4, 256, 0, stream>>>(bufA, bufB, row_ptr, csr_src, dinv, N);
    gemm_bias<128, true><<<(N + 31) / 32, 256, 0, stream>>>(bufB, W2, b2, bufA, N);
    // Layer 3 (no ReLU)
    agg_kernel<128><<<(N + 3) / 4, 256, 0, stream>>>(bufA, bufB, row_ptr, csr_src, dinv, N);
    gemm_bias<128, false><<<(N + 31) / 32, 256, 0, stream>>>(bufB, W3, b3, bufA, N);

    // Pool (batch is sorted -> contiguous per-graph row ranges) + head
    gstart_bs<<<1, 256, 0, stream>>>(batch, gstart, N, G);
    pool_kernel<<<G, 512, 0, stream>>>(bufA, gstart, gpool);
    head_kernel<<<(G * 8 + 255) / 256, 256, 0, stream>>>(gpool, Wh, bh, (float*)d_out, G);
}

// Round 3
// 407.022 us; speedup vs baseline: 1.8583x; 1.2751x over previous
//
#include <hip/hip_runtime.h>

// ---------------- CSR construction ----------------

__global__ void deg_kernel(const int* __restrict__ dst, int* __restrict__ deg, int E) {
    int e = blockIdx.x * 256 + threadIdx.x;
    if (e < E) atomicAdd(&deg[dst[e]], 1);
}

__global__ void dinv_kernel(const int* __restrict__ deg, float* __restrict__ dinv, int n) {
    int i = blockIdx.x * 256 + threadIdx.x;
    if (i < n) dinv[i] = rsqrtf((float)(deg[i] + 1));   // +1 self-loop; deg+1 >= 1
}

__global__ void scan_blocksum(const int* __restrict__ deg, int* __restrict__ bsum, int n) {
    int i = blockIdx.x * 256 + threadIdx.x;
    int v = (i < n) ? (deg[i] + 1) : 0;
    for (int off = 32; off > 0; off >>= 1) v += __shfl_down(v, off, 64);
    __shared__ int ws[4];
    if ((threadIdx.x & 63) == 0) ws[threadIdx.x >> 6] = v;
    __syncthreads();
    if (threadIdx.x == 0) bsum[blockIdx.x] = ws[0] + ws[1] + ws[2] + ws[3];
}

__global__ void scan_offsets(const int* __restrict__ bsum, int* __restrict__ boff, int nblk) {
    __shared__ int buf[256];
    int tid = threadIdx.x;
    int v = (tid < nblk) ? bsum[tid] : 0;
    buf[tid] = v;
    __syncthreads();
    for (int off = 1; off < 256; off <<= 1) {
        int t = (tid >= off) ? buf[tid - off] : 0;
        __syncthreads();
        buf[tid] += t;
        __syncthreads();
    }
    if (tid < nblk) boff[tid] = buf[tid] - v;   // exclusive
}

__global__ void scan_rowptr(const int* __restrict__ deg, const int* __restrict__ boff,
                            int* __restrict__ row_ptr, int* __restrict__ cursor, int n) {
    __shared__ int buf[256];
    int tid = threadIdx.x;
    int i = blockIdx.x * 256 + tid;
    int v = (i < n) ? (deg[i] + 1) : 0;
    buf[tid] = v;
    __syncthreads();
    for (int off = 1; off < 256; off <<= 1) {
        int t = (tid >= off) ? buf[tid - off] : 0;
        __syncthreads();
        buf[tid] += t;
        __syncthreads();
    }
    int excl = buf[tid] - v + boff[blockIdx.x];
    if (i < n) { row_ptr[i] = excl; cursor[i] = excl; }
    if (i == n - 1) row_ptr[n] = excl + v;
}

// Packs (src, dinv[src]) so the agg loops have no dependent dinv load.
__global__ void fill_kernel(const int* __restrict__ src, const int* __restrict__ dst,
                            const float* __restrict__ dinv,
                            int* __restrict__ cursor, int2* __restrict__ csr_pair,
                            int E, int n) {
    int e = blockIdx.x * 256 + threadIdx.x;
    if (e >= E + n) return;
    int s, d;
    if (e < E) { s = src[e]; d = dst[e]; } else { s = e - E; d = s; }
    int pos = atomicAdd(&cursor[d], 1);
    csr_pair[pos] = make_int2(s, __float_as_int(dinv[s]));
}

// ---------------- Aggregation: out[n] = dinv[n] * sum_s dinv[s] * in[s] ----------------
// One wave per node. float4 lanes; C=128: half-waves process 2 edges concurrently
// (manually unrolled x2 -> 4 row loads in flight); C=64: quarter-waves, 4 edges/iter.

template<int C>
__global__ __launch_bounds__(256) void agg_kernel(
        const float* __restrict__ in, float* __restrict__ out,
        const int* __restrict__ row_ptr, const int2* __restrict__ csr_pair,
        const float* __restrict__ dinv, int n) {
    int node = blockIdx.x * 4 + (threadIdx.x >> 6);
    int lane = threadIdx.x & 63;
    if (node >= n) return;
    int beg = row_ptr[node], end = row_ptr[node + 1];
    const float4* in4 = (const float4*)in;

    if (C == 128) {
        int h = lane >> 5;        // which edge of the pair
        int col = lane & 31;      // float4 column
        float4 acc = make_float4(0.f, 0.f, 0.f, 0.f);
        int i = beg + h;
        for (; i + 2 < end; i += 4) {   // 2 edges per half-wave iter -> 4 rows in flight/wave
            int2 p0 = csr_pair[i];
            int2 p1 = csr_pair[i + 2];
            float w0 = __int_as_float(p0.y);
            float w1 = __int_as_float(p1.y);
            float4 v0 = in4[(size_t)p0.x * 32 + col];
            float4 v1 = in4[(size_t)p1.x * 32 + col];
            acc.x = fmaf(w0, v0.x, acc.x); acc.y = fmaf(w0, v0.y, acc.y);
            acc.z = fmaf(w0, v0.z, acc.z); acc.w = fmaf(w0, v0.w, acc.w);
            acc.x = fmaf(w1, v1.x, acc.x); acc.y = fmaf(w1, v1.y, acc.y);
            acc.z = fmaf(w1, v1.z, acc.z); acc.w = fmaf(w1, v1.w, acc.w);
        }
        if (i < end) {
            int2 p = csr_pair[i];
            float w = __int_as_float(p.y);
            float4 v = in4[(size_t)p.x * 32 + col];
            acc.x = fmaf(w, v.x, acc.x); acc.y = fmaf(w, v.y, acc.y);
            acc.z = fmaf(w, v.z, acc.z); acc.w = fmaf(w, v.w, acc.w);
        }
        // combine the two half-wave partials
        acc.x += __shfl_xor(acc.x, 32, 64);
        acc.y += __shfl_xor(acc.y, 32, 64);
        acc.z += __shfl_xor(acc.z, 32, 64);
        acc.w += __shfl_xor(acc.w, 32, 64);
        if (h == 0) {
            float dn = dinv[node];
            ((float4*)out)[(size_t)node * 32 + col] =
                make_float4(acc.x * dn, acc.y * dn, acc.z * dn, acc.w * dn);
        }
    } else {  // C == 64
        int q = lane >> 4;        // which edge of the quad
        int col = lane & 15;
        float4 acc = make_float4(0.f, 0.f, 0.f, 0.f);
        for (int i = beg + q; i < end; i += 4) {   // 4 rows in flight/wave
            int2 p = csr_pair[i];
            float w = __int_as_float(p.y);
            float4 v = in4[(size_t)p.x * 16 + col];
            acc.x = fmaf(w, v.x, acc.x); acc.y = fmaf(w, v.y, acc.y);
            acc.z = fmaf(w, v.z, acc.z); acc.w = fmaf(w, v.w, acc.w);
        }
        acc.x += __shfl_xor(acc.x, 16, 64);
        acc.y += __shfl_xor(acc.y, 16, 64);
        acc.z += __shfl_xor(acc.z, 16, 64);
        acc.w += __shfl_xor(acc.w, 16, 64);
        acc.x += __shfl_xor(acc.x, 32, 64);
        acc.y += __shfl_xor(acc.y, 32, 64);
        acc.z += __shfl_xor(acc.z, 32, 64);
        acc.w += __shfl_xor(acc.w, 32, 64);
        if (q == 0) {
            float dn = dinv[node];
            ((float4*)out)[(size_t)node * 16 + col] =
                make_float4(acc.x * dn, acc.y * dn, acc.z * dn, acc.w * dn);
        }
    }
}

// ---------------- GEMM + bias (+ReLU): [n,K] @ [K,128] ----------------

template<int K, bool RELU>
__global__ __launch_bounds__(256) void gemm_bias(
        const float* __restrict__ A, const float* __restrict__ W,
        const float* __restrict__ b, float* __restrict__ out, int n) {
    __shared__ float Ws[K * 128];
    __shared__ float As[32 * K];
    int tid = threadIdx.x;
    for (int i = tid * 4; i < K * 128; i += 256 * 4)
        *(float4*)&Ws[i] = *(const float4*)&W[i];
    int row0 = blockIdx.x * 32;
    for (int i = tid * 4; i < 32 * K; i += 256 * 4) {
        int r = i / K;
        int k = i - r * K;
        int gr = row0 + r;
        float4 v = make_float4(0.f, 0.f, 0.f, 0.f);
        if (gr < n) v = *(const float4*)&A[(size_t)gr * K + k];
        *(float4*)&As[i] = v;
    }
    __syncthreads();
    int tx = tid & 31;
    int ty = tid >> 5;
    float acc[4][4];
    float4 bv = *(const float4*)&b[tx * 4];
#pragma unroll
    for (int i = 0; i < 4; ++i) { acc[i][0] = bv.x; acc[i][1] = bv.y; acc[i][2] = bv.z; acc[i][3] = bv.w; }
    for (int k = 0; k < K; ++k) {
        float4 wv = *(const float4*)&Ws[k * 128 + tx * 4];
        float av[4];
#pragma unroll
        for (int i = 0; i < 4; ++i) av[i] = As[(ty * 4 + i) * K + k];
#pragma unroll
        for (int i = 0; i < 4; ++i) {
            acc[i][0] = fmaf(av[i], wv.x, acc[i][0]);
            acc[i][1] = fmaf(av[i], wv.y, acc[i][1]);
            acc[i][2] = fmaf(av[i], wv.z, acc[i][2]);
            acc[i][3] = fmaf(av[i], wv.w, acc[i][3]);
        }
    }
#pragma unroll
    for (int i = 0; i < 4; ++i) {
        int gr = row0 + ty * 4 + i;
        if (gr < n) {
            float4 o;
            o.x = RELU ? fmaxf(acc[i][0], 0.f) : acc[i][0];
            o.y = RELU ? fmaxf(acc[i][1], 0.f) : acc[i][1];
            o.z = RELU ? fmaxf(acc[i][2], 0.f) : acc[i][2];
            o.w = RELU ? fmaxf(acc[i][3], 0.f) : acc[i][3];
            *(float4*)&out[(size_t)gr * 128 + tx * 4] = o;
        }
    }
}

// ---------------- Pooling + head ----------------

// batch is sorted: gstart[g] = lower_bound(batch, g). No atomics, handles empty graphs.
__global__ void gstart_bs(const int* __restrict__ batch, int* __restrict__ gstart,
                          int n, int G) {
    int g = blockIdx.x * blockDim.x + threadIdx.x;
    if (g > G) return;
    int lo = 0, hi = n;
    while (lo < hi) {
        int mid = (lo + hi) >> 1;
        if (batch[mid] < g) lo = mid + 1; else hi = mid;
    }
    gstart[g] = lo;
}

__global__ void pool_kernel(const float* __restrict__ h, const int* __restrict__ gstart,
                            float* __restrict__ gout) {
    __shared__ float part[512];
    int g = blockIdx.x;
    int tid = threadIdx.x;
    int c = tid & 127, rs = tid >> 7;
    int beg = gstart[g], end = gstart[g + 1];
    float acc = 0.f;
    for (int nrow = beg + rs; nrow < end; nrow += 4)
        acc += h[(size_t)nrow * 128 + c];
    part[tid] = acc;
    __syncthreads();
    if (rs == 0) {
        float t = part[c] + part[c + 128] + part[c + 256] + part[c + 384];
        gout[g * 128 + c] = t / fmaxf((float)(end - beg), 1.f);
    }
}

__global__ void head_kernel(const float* __restrict__ g, const float* __restrict__ Wh,
                            const float* __restrict__ bh, float* __restrict__ out, int G) {
    int tid = blockIdx.x * blockDim.x + threadIdx.x;
    if (tid >= G * 8) return;
    int gi = tid >> 3, o = tid & 7;
    float acc = bh[o];
    for (int k = 0; k < 128; ++k)
        acc = fmaf(g[gi * 128 + k], Wh[k * 8 + o], acc);
    out[tid] = acc;
}

// ---------------- Launch ----------------

extern "C" void kernel_launch(void* const* d_in, const int* in_sizes, int n_in,
                              void* d_out, int out_size, void* d_ws, size_t ws_size,
                              hipStream_t stream) {
    const float* x  = (const float*)d_in[0];
    const float* W1 = (const float*)d_in[1];
    const float* b1 = (const float*)d_in[2];
    const float* W2 = (const float*)d_in[3];
    const float* b2 = (const float*)d_in[4];
    const float* W3 = (const float*)d_in[5];
    const float* b3 = (const float*)d_in[6];
    const float* Wh = (const float*)d_in[7];
    const float* bh = (const float*)d_in[8];
    const int* edge_index = (const int*)d_in[9];
    const int* batch = (const int*)d_in[10];
    (void)n_in; (void)ws_size;

    const int N = in_sizes[10];
    const int E = in_sizes[9] / 2;
    const int G = out_size / 8;
    const int* esrc = edge_index;
    const int* edst = edge_index + E;

    size_t off = 0;
    auto take = [&](size_t bytes) {
        void* p = (char*)d_ws + off;
        off += (bytes + 255) & ~(size_t)255;
        return p;
    };
    int*   deg      = (int*)take((size_t)N * 4);
    float* dinv     = (float*)take((size_t)N * 4);
    int*   row_ptr  = (int*)take((size_t)(N + 1) * 4);
    int*   cursor   = (int*)take((size_t)N * 4);
    int2*  csr_pair = (int2*)take((size_t)(E + N) * 8);
    int*   bsum     = (int*)take(256 * 4);
    int*   boff     = (int*)take(256 * 4);
    int*   gstart   = (int*)take((size_t)(G + 1) * 4);
    float* gpool    = (float*)take((size_t)G * 128 * 4);
    float* bufA     = (float*)take((size_t)N * 128 * 4);
    float* bufB     = (float*)take((size_t)N * 128 * 4);

    int nblk = (N + 255) / 256;   // 196 for N=50000 (fits single-block scan_offsets)

    hipMemsetAsync(deg, 0, (size_t)N * 4, stream);

    deg_kernel<<<(E + 255) / 256, 256, 0, stream>>>(edst, deg, E);
    dinv_kernel<<<nblk, 256, 0, stream>>>(deg, dinv, N);
    scan_blocksum<<<nblk, 256, 0, stream>>>(deg, bsum, N);
    scan_offsets<<<1, 256, 0, stream>>>(bsum, boff, nblk);
    scan_rowptr<<<nblk, 256, 0, stream>>>(deg, boff, row_ptr, cursor, N);
    fill_kernel<<<(E + N + 255) / 256, 256, 0, stream>>>(esrc, edst, dinv, cursor, csr_pair, E, N);

    // Layer 1: aggregate 64-wide input first (Agg(x)@W1 == Agg(x@W1)), then GEMM+bias+ReLU
    agg_kernel<64><<<(N + 3) / 4, 256, 0, stream>>>(x, bufB, row_ptr, csr_pair, dinv, N);
    gemm_bias<64, true><<<(N + 31) / 32, 256, 0, stream>>>(bufB, W1, b1, bufA, N);
    // Layer 2
    agg_kernel<128><<<(N + 3) / 4, 256, 0, stream>>>(bufA, bufB, row_ptr, csr_pair, dinv, N);
    gemm_bias<128, true><<<(N + 31) / 32, 256, 0, stream>>>(bufB, W2, b2, bufA, N);
    // Layer 3 (no ReLU)
    agg_kernel<128><<<(N + 3) / 4, 256, 0, stream>>>(bufA, bufB, row_ptr, csr_pair, dinv, N);
    gemm_bias<128, false><<<(N + 31) / 32, 256, 0, stream>>>(bufB, W3, b3, bufA, N);

    // Pool (batch is sorted -> contiguous per-graph row ranges) + head
    gstart_bs<<<1, 256, 0, stream>>>(batch, gstart, N, G);
    pool_kernel<<<G, 512, 0, stream>>>(bufA, gstart, gpool);
    head_kernel<<<(G * 8 + 255) / 256, 256, 0, stream>>>(gpool, Wh, bh, (float*)d_out, G);
}

// Round 4
// 380.618 us; speedup vs baseline: 1.9872x; 1.0694x over previous
//
#include <hip/hip_runtime.h>

// ---------------- CSR construction ----------------

// Counts edges per dst AND records each edge's arrival rank (atomicAdd return),
// so the fill pass needs no atomics at all.
__global__ void deg_kernel(const int* __restrict__ dst, int* __restrict__ deg,
                           int* __restrict__ rank, int E) {
    int e = blockIdx.x * 256 + threadIdx.x;
    if (e < E) rank[e] = atomicAdd(&deg[dst[e]], 1);
}

__global__ void dinv_kernel(const int* __restrict__ deg, float* __restrict__ dinv, int n) {
    int i = blockIdx.x * 256 + threadIdx.x;
    if (i < n) dinv[i] = rsqrtf((float)(deg[i] + 1));   // +1 self-loop; deg+1 >= 1
}

__global__ void scan_blocksum(const int* __restrict__ deg, int* __restrict__ bsum, int n) {
    int i = blockIdx.x * 256 + threadIdx.x;
    int v = (i < n) ? (deg[i] + 1) : 0;
    for (int off = 32; off > 0; off >>= 1) v += __shfl_down(v, off, 64);
    __shared__ int ws[4];
    if ((threadIdx.x & 63) == 0) ws[threadIdx.x >> 6] = v;
    __syncthreads();
    if (threadIdx.x == 0) bsum[blockIdx.x] = ws[0] + ws[1] + ws[2] + ws[3];
}

__global__ void scan_offsets(const int* __restrict__ bsum, int* __restrict__ boff, int nblk) {
    __shared__ int buf[256];
    int tid = threadIdx.x;
    int v = (tid < nblk) ? bsum[tid] : 0;
    buf[tid] = v;
    __syncthreads();
    for (int off = 1; off < 256; off <<= 1) {
        int t = (tid >= off) ? buf[tid - off] : 0;
        __syncthreads();
        buf[tid] += t;
        __syncthreads();
    }
    if (tid < nblk) boff[tid] = buf[tid] - v;   // exclusive
}

__global__ void scan_rowptr(const int* __restrict__ deg, const int* __restrict__ boff,
                            int* __restrict__ row_ptr, int n) {
    __shared__ int buf[256];
    int tid = threadIdx.x;
    int i = blockIdx.x * 256 + tid;
    int v = (i < n) ? (deg[i] + 1) : 0;
    buf[tid] = v;
    __syncthreads();
    for (int off = 1; off < 256; off <<= 1) {
        int t = (tid >= off) ? buf[tid - off] : 0;
        __syncthreads();
        buf[tid] += t;
        __syncthreads();
    }
    int excl = buf[tid] - v + boff[blockIdx.x];
    if (i < n) row_ptr[i] = excl;
    if (i == n - 1) row_ptr[n] = excl + v;
}

// Atomic-free fill: pos = row_ptr[dst] + 1 + rank (self-loop deterministically at slot 0).
// Packs (src, dinv[src]); nontemporal scatter store avoids local-L2 partial-line churn.
__global__ void fill_kernel(const int* __restrict__ src, const int* __restrict__ dst,
                            const int* __restrict__ rank, const float* __restrict__ dinv,
                            const int* __restrict__ row_ptr,
                            unsigned long long* __restrict__ csr, int E, int n) {
    int e = blockIdx.x * 256 + threadIdx.x;
    if (e < E) {
        int s = src[e], d = dst[e];
        int pos = row_ptr[d] + 1 + rank[e];
        unsigned long long v =
            ((unsigned long long)__float_as_uint(dinv[s]) << 32) | (unsigned)s;
        __builtin_nontemporal_store(v, &csr[pos]);
    } else if (e < E + n) {
        int s = e - E;
        unsigned long long v =
            ((unsigned long long)__float_as_uint(dinv[s]) << 32) | (unsigned)s;
        __builtin_nontemporal_store(v, &csr[row_ptr[s]]);
    }
}

// ---------------- Aggregation: out[n] = dinv[n] * sum_s dinv[s] * in[s] ----------------
// One wave per node, float4 lanes.
// C=128: 2 half-waves x 4-deep unroll -> 8 row loads in flight per wave.
// C=64 : 4 quarter-waves x 2-deep unroll -> 8 row loads in flight per wave.

template<int C>
__global__ __launch_bounds__(256) void agg_kernel(
        const float* __restrict__ in, float* __restrict__ out,
        const int* __restrict__ row_ptr, const int2* __restrict__ csr_pair,
        const float* __restrict__ dinv, int n) {
    int node = blockIdx.x * 4 + (threadIdx.x >> 6);
    int lane = threadIdx.x & 63;
    if (node >= n) return;
    int beg = row_ptr[node], end = row_ptr[node + 1];
    const float4* in4 = (const float4*)in;

    if (C == 128) {
        int h = lane >> 5;        // which edge of the pair
        int col = lane & 31;      // float4 column
        float4 acc = make_float4(0.f, 0.f, 0.f, 0.f);
        int i = beg + h;
        for (; i + 6 < end; i += 8) {   // 4 edges per half-wave iter
            int2 p0 = csr_pair[i];
            int2 p1 = csr_pair[i + 2];
            int2 p2 = csr_pair[i + 4];
            int2 p3 = csr_pair[i + 6];
            float4 v0 = in4[(size_t)p0.x * 32 + col];
            float4 v1 = in4[(size_t)p1.x * 32 + col];
            float4 v2 = in4[(size_t)p2.x * 32 + col];
            float4 v3 = in4[(size_t)p3.x * 32 + col];
            float w0 = __int_as_float(p0.y), w1 = __int_as_float(p1.y);
            float w2 = __int_as_float(p2.y), w3 = __int_as_float(p3.y);
            acc.x = fmaf(w0, v0.x, acc.x); acc.y = fmaf(w0, v0.y, acc.y);
            acc.z = fmaf(w0, v0.z, acc.z); acc.w = fmaf(w0, v0.w, acc.w);
            acc.x = fmaf(w1, v1.x, acc.x); acc.y = fmaf(w1, v1.y, acc.y);
            acc.z = fmaf(w1, v1.z, acc.z); acc.w = fmaf(w1, v1.w, acc.w);
            acc.x = fmaf(w2, v2.x, acc.x); acc.y = fmaf(w2, v2.y, acc.y);
            acc.z = fmaf(w2, v2.z, acc.z); acc.w = fmaf(w2, v2.w, acc.w);
            acc.x = fmaf(w3, v3.x, acc.x); acc.y = fmaf(w3, v3.y, acc.y);
            acc.z = fmaf(w3, v3.z, acc.z); acc.w = fmaf(w3, v3.w, acc.w);
        }
        for (; i < end; i += 2) {
            int2 p = csr_pair[i];
            float w = __int_as_float(p.y);
            float4 v = in4[(size_t)p.x * 32 + col];
            acc.x = fmaf(w, v.x, acc.x); acc.y = fmaf(w, v.y, acc.y);
            acc.z = fmaf(w, v.z, acc.z); acc.w = fmaf(w, v.w, acc.w);
        }
        // combine the two half-wave partials
        acc.x += __shfl_xor(acc.x, 32, 64);
        acc.y += __shfl_xor(acc.y, 32, 64);
        acc.z += __shfl_xor(acc.z, 32, 64);
        acc.w += __shfl_xor(acc.w, 32, 64);
        if (h == 0) {
            float dn = dinv[node];
            ((float4*)out)[(size_t)node * 32 + col] =
                make_float4(acc.x * dn, acc.y * dn, acc.z * dn, acc.w * dn);
        }
    } else {  // C == 64
        int q = lane >> 4;        // which edge of the quad
        int col = lane & 15;
        float4 acc = make_float4(0.f, 0.f, 0.f, 0.f);
        int i = beg + q;
        for (; i + 4 < end; i += 8) {   // 2 edges per quarter-wave iter
            int2 p0 = csr_pair[i];
            int2 p1 = csr_pair[i + 4];
            float4 v0 = in4[(size_t)p0.x * 16 + col];
            float4 v1 = in4[(size_t)p1.x * 16 + col];
            float w0 = __int_as_float(p0.y), w1 = __int_as_float(p1.y);
            acc.x = fmaf(w0, v0.x, acc.x); acc.y = fmaf(w0, v0.y, acc.y);
            acc.z = fmaf(w0, v0.z, acc.z); acc.w = fmaf(w0, v0.w, acc.w);
            acc.x = fmaf(w1, v1.x, acc.x); acc.y = fmaf(w1, v1.y, acc.y);
            acc.z = fmaf(w1, v1.z, acc.z); acc.w = fmaf(w1, v1.w, acc.w);
        }
        if (i < end) {
            int2 p = csr_pair[i];
            float w = __int_as_float(p.y);
            float4 v = in4[(size_t)p.x * 16 + col];
            acc.x = fmaf(w, v.x, acc.x); acc.y = fmaf(w, v.y, acc.y);
            acc.z = fmaf(w, v.z, acc.z); acc.w = fmaf(w, v.w, acc.w);
        }
        acc.x += __shfl_xor(acc.x, 16, 64);
        acc.y += __shfl_xor(acc.y, 16, 64);
        acc.z += __shfl_xor(acc.z, 16, 64);
        acc.w += __shfl_xor(acc.w, 16, 64);
        acc.x += __shfl_xor(acc.x, 32, 64);
        acc.y += __shfl_xor(acc.y, 32, 64);
        acc.z += __shfl_xor(acc.z, 32, 64);
        acc.w += __shfl_xor(acc.w, 32, 64);
        if (q == 0) {
            float dn = dinv[node];
            ((float4*)out)[(size_t)node * 16 + col] =
                make_float4(acc.x * dn, acc.y * dn, acc.z * dn, acc.w * dn);
        }
    }
}

// ---------------- GEMM + bias (+ReLU): [n,K] @ [K,128] ----------------

template<int K, bool RELU>
__global__ __launch_bounds__(256) void gemm_bias(
        const float* __restrict__ A, const float* __restrict__ W,
        const float* __restrict__ b, float* __restrict__ out, int n) {
    __shared__ float Ws[K * 128];
    __shared__ float As[32 * K];
    int tid = threadIdx.x;
    for (int i = tid * 4; i < K * 128; i += 256 * 4)
        *(float4*)&Ws[i] = *(const float4*)&W[i];
    int row0 = blockIdx.x * 32;
    for (int i = tid * 4; i < 32 * K; i += 256 * 4) {
        int r = i / K;
        int k = i - r * K;
        int gr = row0 + r;
        float4 v = make_float4(0.f, 0.f, 0.f, 0.f);
        if (gr < n) v = *(const float4*)&A[(size_t)gr * K + k];
        *(float4*)&As[i] = v;
    }
    __syncthreads();
    int tx = tid & 31;
    int ty = tid >> 5;
    float acc[4][4];
    float4 bv = *(const float4*)&b[tx * 4];
#pragma unroll
    for (int i = 0; i < 4; ++i) { acc[i][0] = bv.x; acc[i][1] = bv.y; acc[i][2] = bv.z; acc[i][3] = bv.w; }
    for (int k = 0; k < K; ++k) {
        float4 wv = *(const float4*)&Ws[k * 128 + tx * 4];
        float av[4];
#pragma unroll
        for (int i = 0; i < 4; ++i) av[i] = As[(ty * 4 + i) * K + k];
#pragma unroll
        for (int i = 0; i < 4; ++i) {
            acc[i][0] = fmaf(av[i], wv.x, acc[i][0]);
            acc[i][1] = fmaf(av[i], wv.y, acc[i][1]);
            acc[i][2] = fmaf(av[i], wv.z, acc[i][2]);
            acc[i][3] = fmaf(av[i], wv.w, acc[i][3]);
        }
    }
#pragma unroll
    for (int i = 0; i < 4; ++i) {
        int gr = row0 + ty * 4 + i;
        if (gr < n) {
            float4 o;
            o.x = RELU ? fmaxf(acc[i][0], 0.f) : acc[i][0];
            o.y = RELU ? fmaxf(acc[i][1], 0.f) : acc[i][1];
            o.z = RELU ? fmaxf(acc[i][2], 0.f) : acc[i][2];
            o.w = RELU ? fmaxf(acc[i][3], 0.f) : acc[i][3];
            *(float4*)&out[(size_t)gr * 128 + tx * 4] = o;
        }
    }
}

// ---------------- Pooling + head ----------------

// batch is sorted: gstart[g] = lower_bound(batch, g). No atomics, handles empty graphs.
__global__ void gstart_bs(const int* __restrict__ batch, int* __restrict__ gstart,
                          int n, int G) {
    int g = blockIdx.x * blockDim.x + threadIdx.x;
    if (g > G) return;
    int lo = 0, hi = n;
    while (lo < hi) {
        int mid = (lo + hi) >> 1;
        if (batch[mid] < g) lo = mid + 1; else hi = mid;
    }
    gstart[g] = lo;
}

__global__ void pool_kernel(const float* __restrict__ h, const int* __restrict__ gstart,
                            float* __restrict__ gout) {
    __shared__ float part[512];
    int g = blockIdx.x;
    int tid = threadIdx.x;
    int c = tid & 127, rs = tid >> 7;
    int beg = gstart[g], end = gstart[g + 1];
    float acc = 0.f;
    for (int nrow = beg + rs; nrow < end; nrow += 4)
        acc += h[(size_t)nrow * 128 + c];
    part[tid] = acc;
    __syncthreads();
    if (rs == 0) {
        float t = part[c] + part[c + 128] + part[c + 256] + part[c + 384];
        gout[g * 128 + c] = t / fmaxf((float)(end - beg), 1.f);
    }
}

__global__ void head_kernel(const float* __restrict__ g, const float* __restrict__ Wh,
                            const float* __restrict__ bh, float* __restrict__ out, int G) {
    int tid = blockIdx.x * blockDim.x + threadIdx.x;
    if (tid >= G * 8) return;
    int gi = tid >> 3, o = tid & 7;
    float acc = bh[o];
    for (int k = 0; k < 128; ++k)
        acc = fmaf(g[gi * 128 + k], Wh[k * 8 + o], acc);
    out[tid] = acc;
}

// ---------------- Launch ----------------

extern "C" void kernel_launch(void* const* d_in, const int* in_sizes, int n_in,
                              void* d_out, int out_size, void* d_ws, size_t ws_size,
                              hipStream_t stream) {
    const float* x  = (const float*)d_in[0];
    const float* W1 = (const float*)d_in[1];
    const float* b1 = (const float*)d_in[2];
    const float* W2 = (const float*)d_in[3];
    const float* b2 = (const float*)d_in[4];
    const float* W3 = (const float*)d_in[5];
    const float* b3 = (const float*)d_in[6];
    const float* Wh = (const float*)d_in[7];
    const float* bh = (const float*)d_in[8];
    const int* edge_index = (const int*)d_in[9];
    const int* batch = (const int*)d_in[10];
    (void)n_in; (void)ws_size;

    const int N = in_sizes[10];
    const int E = in_sizes[9] / 2;
    const int G = out_size / 8;
    const int* esrc = edge_index;
    const int* edst = edge_index + E;

    size_t off = 0;
    auto take = [&](size_t bytes) {
        void* p = (char*)d_ws + off;
        off += (bytes + 255) & ~(size_t)255;
        return p;
    };
    int*   deg      = (int*)take((size_t)N * 4);
    float* dinv     = (float*)take((size_t)N * 4);
    int*   row_ptr  = (int*)take((size_t)(N + 1) * 4);
    int*   rank     = (int*)take((size_t)E * 4);
    unsigned long long* csr = (unsigned long long*)take((size_t)(E + N) * 8);
    int*   bsum     = (int*)take(256 * 4);
    int*   boff     = (int*)take(256 * 4);
    int*   gstart   = (int*)take((size_t)(G + 1) * 4);
    float* gpool    = (float*)take((size_t)G * 128 * 4);
    float* bufA     = (float*)take((size_t)N * 128 * 4);
    float* bufB     = (float*)take((size_t)N * 128 * 4);

    int nblk = (N + 255) / 256;   // 196 for N=50000 (fits single-block scan_offsets)

    hipMemsetAsync(deg, 0, (size_t)N * 4, stream);

    deg_kernel<<<(E + 255) / 256, 256, 0, stream>>>(edst, deg, rank, E);
    dinv_kernel<<<nblk, 256, 0, stream>>>(deg, dinv, N);
    scan_blocksum<<<nblk, 256, 0, stream>>>(deg, bsum, N);
    scan_offsets<<<1, 256, 0, stream>>>(bsum, boff, nblk);
    scan_rowptr<<<nblk, 256, 0, stream>>>(deg, boff, row_ptr, N);
    fill_kernel<<<(E + N + 255) / 256, 256, 0, stream>>>(esrc, edst, rank, dinv, row_ptr, csr, E, N);

    const int2* csr_pair = (const int2*)csr;

    // Layer 1: aggregate 64-wide input first (Agg(x)@W1 == Agg(x@W1)), then GEMM+bias+ReLU
    agg_kernel<64><<<(N + 3) / 4, 256, 0, stream>>>(x, bufB, row_ptr, csr_pair, dinv, N);
    gemm_bias<64, true><<<(N + 31) / 32, 256, 0, stream>>>(bufB, W1, b1, bufA, N);
    // Layer 2
    agg_kernel<128><<<(N + 3) / 4, 256, 0, stream>>>(bufA, bufB, row_ptr, csr_pair, dinv, N);
    gemm_bias<128, true><<<(N + 31) / 32, 256, 0, stream>>>(bufB, W2, b2, bufA, N);
    // Layer 3 (no ReLU)
    agg_kernel<128><<<(N + 3) / 4, 256, 0, stream>>>(bufA, bufB, row_ptr, csr_pair, dinv, N);
    gemm_bias<128, false><<<(N + 31) / 32, 256, 0, stream>>>(bufB, W3, b3, bufA, N);

    // Pool (batch is sorted -> contiguous per-graph row ranges) + head
    gstart_bs<<<1, 256, 0, stream>>>(batch, gstart, N, G);
    pool_kernel<<<G, 512, 0, stream>>>(bufA, gstart, gpool);
    head_kernel<<<(G * 8 + 255) / 256, 256, 0, stream>>>(gpool, Wh, bh, (float*)d_out, G);
}